// Round 7
// baseline (257.249 us; speedup 1.0000x reference)
//
#include <hip/hip_runtime.h>

typedef __attribute__((ext_vector_type(8))) short s16x8;
typedef __attribute__((ext_vector_type(4))) float fx4;
typedef __attribute__((ext_vector_type(4))) int ix4;

#define B_SZ 4
#define T_SZ 2048
#define DM 1024
#define NH 16
#define DK 64
#define M_SZ (B_SZ * T_SZ)   // 8192
#define NINF (-__builtin_inff())

__device__ __forceinline__ unsigned short f2bf(float f) {
    unsigned int u = __float_as_uint(f);
    unsigned int r = u + 0x7fffu + ((u >> 16) & 1u);
    return (unsigned short)(r >> 16);
}

__device__ __forceinline__ unsigned cvtpk(float lo, float hi) {
    unsigned r;
    asm("v_cvt_pk_bf16_f32 %0, %1, %2" : "=v"(r) : "v"(lo), "v"(hi));
    return r;
}

__device__ __forceinline__ void async16(const unsigned short* g, unsigned short* l) {
    __builtin_amdgcn_global_load_lds(
        (const __attribute__((address_space(1))) unsigned int*)g,
        (__attribute__((address_space(3))) unsigned int*)l, 16, 0, 0);
}

// ---------------- cast fp32 -> bf16 (vectorized) ----------------
__global__ void cast_f32_bf16(const float* __restrict__ src, unsigned short* __restrict__ dst, int n) {
    int i = (blockIdx.x * blockDim.x + threadIdx.x) * 4;
    int stride = gridDim.x * blockDim.x * 4;
    for (; i + 3 < n; i += stride) {
        float4 v = *(const float4*)(src + i);
        ushort4 o;
        o.x = f2bf(v.x); o.y = f2bf(v.y); o.z = f2bf(v.z); o.w = f2bf(v.w);
        *(ushort4*)(dst + i) = o;
    }
}

// fused cast of the 4 weight matrices (dsts contiguous at dst + y*1M)
__global__ void cast_w4(const float* __restrict__ s0, const float* __restrict__ s1,
                        const float* __restrict__ s2, const float* __restrict__ s3,
                        unsigned short* __restrict__ dst) {
    const float* s = (blockIdx.y == 0) ? s0 : (blockIdx.y == 1) ? s1 : (blockIdx.y == 2) ? s2 : s3;
    unsigned short* d = dst + (size_t)blockIdx.y * (DM * DM);
    int i = (blockIdx.x * blockDim.x + threadIdx.x) * 4;
    int stride = gridDim.x * blockDim.x * 4;
    for (; i + 3 < DM * DM; i += stride) {
        float4 v = *(const float4*)(s + i);
        ushort4 o;
        o.x = f2bf(v.x); o.y = f2bf(v.y); o.z = f2bf(v.z); o.w = f2bf(v.w);
        *(ushort4*)(d + i) = o;
    }
}

// ---------------- transpose bf16: src[M_SZ][DM] -> dst[DM][M_SZ] ----------------
__global__ __launch_bounds__(256) void transpose_bf16(const unsigned short* __restrict__ src,
                                                      unsigned short* __restrict__ dst) {
    __shared__ unsigned short tl[64][72];
    const int t = threadIdx.x;
    const int m0 = blockIdx.x * 64, n0 = blockIdx.y * 64;
    const int r = t >> 3, c8 = (t & 7) * 8;
    union { ix4 v; unsigned short u[8]; } a0, a1;
    a0.v = *(const ix4*)(src + (long)(m0 + r) * DM + n0 + c8);
    a1.v = *(const ix4*)(src + (long)(m0 + 32 + r) * DM + n0 + c8);
#pragma unroll
    for (int j = 0; j < 8; ++j) {
        tl[c8 + j][r] = a0.u[j];
        tl[c8 + j][32 + r] = a1.u[j];
    }
    __syncthreads();
    ix4 w0 = *(const ix4*)&tl[r][c8];
    ix4 w1 = *(const ix4*)&tl[32 + r][c8];
    *(ix4*)(dst + (long)(n0 + r) * M_SZ + m0 + c8) = w0;
    *(ix4*)(dst + (long)(n0 + 32 + r) * M_SZ + m0 + c8) = w1;
}

// ---------------- GEMM: C[M][N] = A[M][K] * Bw[N][K]^T ----------------
// 256x128 tile, 512 threads (8 waves, 4m x 2n), 2-phase dbuf, counted vmcnt(3).
template<int OUT_BF16>
__global__ __launch_bounds__(512) void gemm_bt(const unsigned short* __restrict__ A,
                                               const unsigned short* __restrict__ Bw,
                                               void* __restrict__ Cout,
                                               int M, int N, int K, float scale) {
    __shared__ __align__(16) unsigned short As[2][256 * 32];
    __shared__ __align__(16) unsigned short Bs[2][128 * 32];

    const int t = threadIdx.x;
    const int lane = t & 63;
    const int w = t >> 6;                    // 0..7
    const int wm = w >> 1, wn = w & 1;       // 4 x 2 wave grid
    const int lrow = lane & 15, lk = lane >> 4;
    const int m0 = blockIdx.y * 256, n0 = blockIdx.x * 128;

    fx4 acc[4][4] = {};

    const int arow = t >> 2;                 // 0..127
    const int acol = (t & 3) * 8;
    const unsigned short* Ag = A + (long)(m0 + arow) * K + acol;
    const unsigned short* Bg = Bw + (long)(n0 + arow) * K + acol;
    const int lds0 = t * 8;                  // 0..4088
    const int nk = K / 32;

    async16(Ag, &As[0][lds0]);
    async16(Ag + 128 * K, &As[0][lds0 + 128 * 32]);
    async16(Bg, &Bs[0][lds0]);

    for (int kt = 0; kt < nk; ++kt) {
        const int cur = kt & 1;
        if (kt + 1 < nk) {
            const int ko = (kt + 1) * 32;
            async16(Ag + ko, &As[cur ^ 1][lds0]);
            async16(Ag + 128 * K + ko, &As[cur ^ 1][lds0 + 128 * 32]);
            async16(Bg + ko, &Bs[cur ^ 1][lds0]);
            asm volatile("s_waitcnt vmcnt(3)" ::: "memory");
        } else {
            asm volatile("s_waitcnt vmcnt(0)" ::: "memory");
        }
        __syncthreads();

        s16x8 af[4], bf[4];
#pragma unroll
        for (int i = 0; i < 4; ++i)
            af[i] = *(const s16x8*)&As[cur][(wm * 64 + i * 16 + lrow) * 32 + lk * 8];
#pragma unroll
        for (int i = 0; i < 4; ++i)
            bf[i] = *(const s16x8*)&Bs[cur][(wn * 64 + i * 16 + lrow) * 32 + lk * 8];
#pragma unroll
        for (int i = 0; i < 4; ++i)
#pragma unroll
            for (int j = 0; j < 4; ++j)
                acc[i][j] = __builtin_amdgcn_mfma_f32_16x16x32_bf16(af[i], bf[j], acc[i][j], 0, 0, 0);
        __syncthreads();
    }

#pragma unroll
    for (int i = 0; i < 4; ++i)
#pragma unroll
        for (int j = 0; j < 4; ++j)
#pragma unroll
            for (int r = 0; r < 4; ++r) {
                int row = m0 + wm * 64 + i * 16 + lk * 4 + r;
                int col = n0 + wn * 64 + j * 16 + lrow;
                float v = acc[i][j][r] * scale;
                if (OUT_BF16)
                    ((unsigned short*)Cout)[(long)row * N + col] = f2bf(v);
                else
                    ((float*)Cout)[(long)row * N + col] = v;
            }
}

// ---------------- Flash attention: swapped-S^T, 4 waves x 32 q-rows, Vt async16 staging ----------------
// Grid: (64=hb, 16=qb'). Vt is V transposed [DM][M_SZ]: both K and V tiles stage via
// global_load_lds with chunk-XOR pre-swizzled source (rule 21); no in-kernel transpose.
__global__ __launch_bounds__(256, 4) void attn_kernel(const unsigned short* __restrict__ Q,
                                                      const unsigned short* __restrict__ Kb,
                                                      const unsigned short* __restrict__ Vt,
                                                      unsigned short* __restrict__ O) {
    __shared__ __align__(16) unsigned short Ks[2][64 * 64];   // [kv][d-chunk swz]
    __shared__ __align__(16) unsigned short Vs[2][64 * 64];   // [d][kv-chunk swz]
    __shared__ __align__(16) unsigned short Pl[4][16 * 72];   // per-wave P

    const int t = threadIdx.x;
    const int lane = t & 63, w = t >> 6;
    const int lrow = lane & 15, lk = lane >> 4;
    const int hb = blockIdx.x;
    const int h = hb & 15, b = hb >> 4;
    const int qb = 15 - blockIdx.y;                // heavy blocks dispatch first
    const int row0 = b * T_SZ;
    const int q0w = qb * 128 + w * 32;

    s16x8 qf[2][2];
#pragma unroll
    for (int hh = 0; hh < 2; ++hh) {
        const unsigned short* qp = Q + (long)(row0 + q0w + hh * 16 + lrow) * DM + h * DK + lk * 8;
        qf[hh][0] = *(const s16x8*)qp;
        qf[hh][1] = *(const s16x8*)(qp + 32);
    }

    fx4 acc[2][4] = {};
    float mrun[2] = {NINF, NINF}, lsum[2] = {0.f, 0.f};

    // staging: 256 threads cover 32 rows per issue; 2 issues per 64-row tile
    const int srow = t >> 3;                               // 0..31
    const int chk = (t & 7) ^ (srow & 7);                  // source pre-swizzle
    const unsigned short* Kg = Kb + (long)(row0 + srow) * DM + h * DK + chk * 8;
    const unsigned short* Vg = Vt + (long)(h * DK + srow) * M_SZ + row0 + chk * 8;
    unsigned short* Kl = &Ks[0][t * 8];
    unsigned short* Vl = &Vs[0][t * 8];

    const int nt = 2 * qb + 2;

    // prologue: stage tile 0 into buffer 0
    async16(Kg, Kl);
    async16(Kg + 32 * DM, Kl + 2048);
    async16(Vg, Vl);
    async16(Vg + 32 * (long)M_SZ, Vl + 2048);
    asm volatile("s_waitcnt vmcnt(0)" ::: "memory");
    __syncthreads();

    for (int kt = 0; kt < nt; ++kt) {
        const int cur = kt & 1;
        const bool pre = (kt + 1 < nt);
        if (pre) {
            const long koff = (long)(kt + 1) * 64 * DM;
            const int voff = (kt + 1) * 64;
            async16(Kg + koff, Kl + (cur ^ 1) * 4096);
            async16(Kg + koff + 32 * DM, Kl + (cur ^ 1) * 4096 + 2048);
            async16(Vg + voff, Vl + (cur ^ 1) * 4096);
            async16(Vg + voff + 32 * (long)M_SZ, Vl + (cur ^ 1) * 4096 + 2048);
        }
        const int kv0 = kt * 64;
        if (kv0 <= q0w + 31) {
            const char* ksb = (const char*)&Ks[cur][0];
            float p[2][4][4];
            float pm0 = NINF, pm1 = NINF;
            // ---- S^T = K·Q^T for both halves with kf reuse ----
#pragma unroll
            for (int sub = 0; sub < 4; ++sub) {
                const int kv0s = kv0 + sub * 16;
                if (kv0s <= q0w + 31) {          // half 1 active
                    const int rb = (sub * 16 + lrow) << 7;
                    const int sw = (lrow & 7) << 4;
                    const s16x8 kf0 = *(const s16x8*)(ksb + (rb + ((lk * 16) ^ sw)));
                    const s16x8 kf1 = *(const s16x8*)(ksb + (rb + ((64 + lk * 16) ^ sw)));
                    fx4 s1 = {};
                    s1 = __builtin_amdgcn_mfma_f32_16x16x32_bf16(kf0, qf[1][0], s1, 0, 0, 0);
                    s1 = __builtin_amdgcn_mfma_f32_16x16x32_bf16(kf1, qf[1][1], s1, 0, 0, 0);
                    if (kv0s + 15 > q0w + 16) {
#pragma unroll
                        for (int r = 0; r < 4; ++r)
                            if (kv0s + lk * 4 + r > q0w + 16 + lrow) s1[r] = NINF;
                    }
#pragma unroll
                    for (int r = 0; r < 4; ++r) { p[1][sub][r] = s1[r]; pm1 = fmaxf(pm1, s1[r]); }
                    if (kv0s <= q0w + 15) {      // half 0 active
                        fx4 s0 = {};
                        s0 = __builtin_amdgcn_mfma_f32_16x16x32_bf16(kf0, qf[0][0], s0, 0, 0, 0);
                        s0 = __builtin_amdgcn_mfma_f32_16x16x32_bf16(kf1, qf[0][1], s0, 0, 0, 0);
                        if (kv0s + 15 > q0w) {
#pragma unroll
                            for (int r = 0; r < 4; ++r)
                                if (kv0s + lk * 4 + r > q0w + lrow) s0[r] = NINF;
                        }
#pragma unroll
                        for (int r = 0; r < 4; ++r) { p[0][sub][r] = s0[r]; pm0 = fmaxf(pm0, s0[r]); }
                    } else {
#pragma unroll
                        for (int r = 0; r < 4; ++r) p[0][sub][r] = NINF;
                    }
                } else {
#pragma unroll
                    for (int r = 0; r < 4; ++r) { p[0][sub][r] = NINF; p[1][sub][r] = NINF; }
                }
            }
            // ---- online softmax per half (defer-max THR=8) ----
            float pmv[2] = {pm0, pm1};
#pragma unroll
            for (int hh = 0; hh < 2; ++hh) {
                float pm = pmv[hh];
                pm = fmaxf(pm, __shfl_xor(pm, 16));
                pm = fmaxf(pm, __shfl_xor(pm, 32));
                if (__any(pm > mrun[hh] + 8.f)) {
                    const float mnew = fmaxf(mrun[hh], pm);
                    const float sc = exp2f(mrun[hh] - mnew);
                    mrun[hh] = mnew;
                    lsum[hh] *= sc;
#pragma unroll
                    for (int r = 0; r < 4; ++r) {
                        const float scr = __shfl(sc, lk * 4 + r);
                        acc[hh][0][r] *= scr; acc[hh][1][r] *= scr;
                        acc[hh][2][r] *= scr; acc[hh][3][r] *= scr;
                    }
                }
                float ps = 0.f;
#pragma unroll
                for (int sub = 0; sub < 4; ++sub)
#pragma unroll
                    for (int r = 0; r < 4; ++r) {
                        const float pv = exp2f(p[hh][sub][r] - mrun[hh]);
                        p[hh][sub][r] = pv;
                        ps += pv;
                    }
                ps += __shfl_xor(ps, 16);
                ps += __shfl_xor(ps, 32);
                lsum[hh] += ps;
            }
            // ---- pack P per half through per-wave LDS (cvt_pk; sequential reuse) ----
            s16x8 pf[2][2];
#pragma unroll
            for (int hh = 0; hh < 2; ++hh) {
#pragma unroll
                for (int sub = 0; sub < 4; ++sub) {
                    uint2 pw;
                    pw.x = cvtpk(p[hh][sub][0], p[hh][sub][1]);
                    pw.y = cvtpk(p[hh][sub][2], p[hh][sub][3]);
                    *(uint2*)&Pl[w][lrow * 72 + sub * 16 + lk * 4] = pw;
                }
                pf[hh][0] = *(const s16x8*)&Pl[w][lrow * 72 + lk * 8];
                pf[hh][1] = *(const s16x8*)&Pl[w][lrow * 72 + 32 + lk * 8];
            }
            // ---- O += P·V with vf reuse across halves ----
#pragma unroll
            for (int s = 0; s < 2; ++s) {
                if (kv0 + s * 32 <= q0w + 31) {
                    const bool h0a = (kv0 + s * 32 <= q0w + 15);
#pragma unroll
                    for (int nf = 0; nf < 4; ++nf) {
                        const int d = nf * 16 + lrow;
                        const s16x8 vf = *(const s16x8*)&Vs[cur][d * 64 + (((s * 4 + lk) ^ (lrow & 7)) << 3)];
                        if (h0a)
                            acc[0][nf] = __builtin_amdgcn_mfma_f32_16x16x32_bf16(pf[0][s], vf, acc[0][nf], 0, 0, 0);
                        acc[1][nf] = __builtin_amdgcn_mfma_f32_16x16x32_bf16(pf[1][s], vf, acc[1][nf], 0, 0, 0);
                    }
                }
            }
        }
        asm volatile("s_waitcnt vmcnt(0)" ::: "memory");
        __syncthreads();
    }

    // ---- epilogue ----
#pragma unroll
    for (int hh = 0; hh < 2; ++hh) {
        float linv[4];
#pragma unroll
        for (int r = 0; r < 4; ++r) linv[r] = 1.f / __shfl(lsum[hh], lk * 4 + r);
        unsigned short* op = O + (long)(row0 + q0w + hh * 16) * DM + h * DK;
#pragma unroll
        for (int nf = 0; nf < 4; ++nf)
#pragma unroll
            for (int r = 0; r < 4; ++r)
                op[(long)(lk * 4 + r) * DM + nf * 16 + lrow] = f2bf(acc[hh][nf][r] * linv[r]);
    }
}

extern "C" void kernel_launch(void* const* d_in, const int* in_sizes, int n_in,
                              void* d_out, int out_size, void* d_ws, size_t ws_size,
                              hipStream_t stream) {
    const float* x  = (const float*)d_in[0];
    const float* Wq = (const float*)d_in[1];
    const float* Wk = (const float*)d_in[2];
    const float* Wv = (const float*)d_in[3];
    const float* Wo = (const float*)d_in[4];
    float* out = (float*)d_out;

    unsigned short* wsu = (unsigned short*)d_ws;
    unsigned short* xb  = wsu;                  // 8,388,608 elems
    unsigned short* wqb = xb + 8388608;         // 4 x 1,048,576 (contiguous)
    unsigned short* wkb = wqb + 1048576;
    unsigned short* wvb = wkb + 1048576;
    unsigned short* wob = wvb + 1048576;
    unsigned short* Qs  = wob + 1048576;        // 8,388,608
    unsigned short* Ob  = Qs + 8388608;         // 8,388,608 (V row-major temp, then O)

    unsigned short* Kb = (unsigned short*)d_out;        // 16MB in d_out
    unsigned short* Vt = Kb + 8388608;                  // 16MB in d_out (V transposed)

    cast_f32_bf16<<<2048, 256, 0, stream>>>(x, xb, M_SZ * DM);
    cast_w4<<<dim3(256, 4), 256, 0, stream>>>(Wq, Wk, Wv, Wo, wqb);

    dim3 ggrid(DM / 128, M_SZ / 256);  // (8, 32)
    const float qscale = 0.125f * 1.44269504088896340736f;  // (1/sqrt(dk)) * log2(e)
    gemm_bt<1><<<ggrid, 512, 0, stream>>>(xb, wqb, Qs, M_SZ, DM, DM, qscale);
    gemm_bt<1><<<ggrid, 512, 0, stream>>>(xb, wkb, Kb, M_SZ, DM, DM, 1.f);
    gemm_bt<1><<<ggrid, 512, 0, stream>>>(xb, wvb, Ob, M_SZ, DM, DM, 1.f);   // V row-major temp

    transpose_bf16<<<dim3(M_SZ / 64, DM / 64), 256, 0, stream>>>(Ob, Vt);

    dim3 agrid(64, 16);                // x = (b,h) -> fixed XCD; y -> qb (heavy first)
    attn_kernel<<<agrid, 256, 0, stream>>>(Qs, Kb, Vt, Ob);   // overwrites V temp with O

    gemm_bt<0><<<ggrid, 512, 0, stream>>>(Ob, wob, out, M_SZ, DM, DM, 1.f);
}

// Round 8
// 208.398 us; speedup vs baseline: 1.2344x; 1.2344x over previous
//
#include <hip/hip_runtime.h>

typedef __attribute__((ext_vector_type(8))) short s16x8;
typedef __attribute__((ext_vector_type(4))) float fx4;
typedef __attribute__((ext_vector_type(4))) int ix4;

#define B_SZ 4
#define T_SZ 2048
#define DM 1024
#define NH 16
#define DK 64
#define M_SZ (B_SZ * T_SZ)   // 8192
#define NINF (-__builtin_inff())
#define QSCALE (0.125f * 1.44269504088896340736f)

__device__ __forceinline__ unsigned short f2bf(float f) {
    unsigned int u = __float_as_uint(f);
    unsigned int r = u + 0x7fffu + ((u >> 16) & 1u);
    return (unsigned short)(r >> 16);
}

__device__ __forceinline__ unsigned cvtpk(float lo, float hi) {
    unsigned r;
    asm("v_cvt_pk_bf16_f32 %0, %1, %2" : "=v"(r) : "v"(lo), "v"(hi));
    return r;
}

__device__ __forceinline__ void async16(const unsigned short* g, unsigned short* l) {
    __builtin_amdgcn_global_load_lds(
        (const __attribute__((address_space(1))) unsigned int*)g,
        (__attribute__((address_space(3))) unsigned int*)l, 16, 0, 0);
}

// ---------------- cast fp32 -> bf16 (vectorized) ----------------
__global__ void cast_f32_bf16(const float* __restrict__ src, unsigned short* __restrict__ dst, int n) {
    int i = (blockIdx.x * blockDim.x + threadIdx.x) * 4;
    int stride = gridDim.x * blockDim.x * 4;
    for (; i + 3 < n; i += stride) {
        float4 v = *(const float4*)(src + i);
        ushort4 o;
        o.x = f2bf(v.x); o.y = f2bf(v.y); o.z = f2bf(v.z); o.w = f2bf(v.w);
        *(ushort4*)(dst + i) = o;
    }
}

// fused cast of the 4 weight matrices (dsts contiguous at dst + y*1M)
__global__ void cast_w4(const float* __restrict__ s0, const float* __restrict__ s1,
                        const float* __restrict__ s2, const float* __restrict__ s3,
                        unsigned short* __restrict__ dst) {
    const float* s = (blockIdx.y == 0) ? s0 : (blockIdx.y == 1) ? s1 : (blockIdx.y == 2) ? s2 : s3;
    unsigned short* d = dst + (size_t)blockIdx.y * (DM * DM);
    int i = (blockIdx.x * blockDim.x + threadIdx.x) * 4;
    int stride = gridDim.x * blockDim.x * 4;
    for (; i + 3 < DM * DM; i += stride) {
        float4 v = *(const float4*)(s + i);
        ushort4 o;
        o.x = f2bf(v.x); o.y = f2bf(v.y); o.z = f2bf(v.z); o.w = f2bf(v.w);
        *(ushort4*)(d + i) = o;
    }
}

// ---------------- fused QKV GEMM (R6-verified 128x128 / 256-thr structure) ----------------
// grid (24, 64): which = x>>3 selects {Q, K, V}; n0l = (x&7)*128.
// Q -> Qs (scaled), K -> Kb (row-major), V -> Vt (TRANSPOSED via LDS epilogue).
__global__ __launch_bounds__(256) void gemm_qkv(const unsigned short* __restrict__ A,
                                                const unsigned short* __restrict__ Wqkv,
                                                unsigned short* __restrict__ Qs,
                                                unsigned short* __restrict__ Kb,
                                                unsigned short* __restrict__ Vt) {
    __shared__ __align__(16) unsigned short smem[16896];  // As|Bs (32KB) then reused as tl[128][132]

    const int t = threadIdx.x;
    const int lane = t & 63;
    const int w = t >> 6;
    const int wm = w >> 1, wn = w & 1;
    const int lrow = lane & 15, lk = lane >> 4;
    const int which = blockIdx.x >> 3;
    const int n0l = (blockIdx.x & 7) * 128;
    const int m0 = blockIdx.y * 128;
    const int K = DM;

    fx4 acc[4][4] = {};

    const int arow = t >> 2;
    const int acol = (t & 3) * 8;
    const unsigned short* Ag = A + (long)(m0 + arow) * K + acol;
    const unsigned short* Bg = Wqkv + (size_t)which * (DM * DM) + (long)(n0l + arow) * K + acol;
    const int lds0 = t * 8;
    const int nk = K / 32;

    async16(Ag, &smem[lds0]);
    async16(Ag + 64 * K, &smem[lds0 + 2048]);
    async16(Bg, &smem[8192 + lds0]);
    async16(Bg + 64 * K, &smem[8192 + lds0 + 2048]);

    for (int kt = 0; kt < nk; ++kt) {
        const int cur = kt & 1;
        if (kt + 1 < nk) {
            const int ko = (kt + 1) * 32;
            const int nb = (cur ^ 1) * 4096;
            async16(Ag + ko, &smem[nb + lds0]);
            async16(Ag + 64 * K + ko, &smem[nb + lds0 + 2048]);
            async16(Bg + ko, &smem[8192 + nb + lds0]);
            async16(Bg + 64 * K + ko, &smem[8192 + nb + lds0 + 2048]);
            asm volatile("s_waitcnt vmcnt(4)" ::: "memory");
        } else {
            asm volatile("s_waitcnt vmcnt(0)" ::: "memory");
        }
        __syncthreads();

        s16x8 af[4], bf[4];
#pragma unroll
        for (int i = 0; i < 4; ++i)
            af[i] = *(const s16x8*)&smem[cur * 4096 + (wm * 64 + i * 16 + lrow) * 32 + lk * 8];
#pragma unroll
        for (int i = 0; i < 4; ++i)
            bf[i] = *(const s16x8*)&smem[8192 + cur * 4096 + (wn * 64 + i * 16 + lrow) * 32 + lk * 8];
#pragma unroll
        for (int i = 0; i < 4; ++i)
#pragma unroll
            for (int j = 0; j < 4; ++j)
                acc[i][j] = __builtin_amdgcn_mfma_f32_16x16x32_bf16(af[i], bf[j], acc[i][j], 0, 0, 0);
        __syncthreads();
    }

    if (which < 2) {
        unsigned short* dst = (which == 0) ? Qs : Kb;
        const float sc = (which == 0) ? QSCALE : 1.f;
#pragma unroll
        for (int i = 0; i < 4; ++i)
#pragma unroll
            for (int j = 0; j < 4; ++j)
#pragma unroll
                for (int r = 0; r < 4; ++r) {
                    int row = m0 + wm * 64 + i * 16 + lk * 4 + r;
                    int col = n0l + wn * 64 + j * 16 + lrow;
                    dst[(long)row * DM + col] = f2bf(acc[i][j][r] * sc);
                }
    } else {
        // V: transpose the 128x128 tile through LDS, store coalesced to Vt[DM][M_SZ]
#pragma unroll
        for (int i = 0; i < 4; ++i)
#pragma unroll
            for (int j = 0; j < 4; ++j) {
                const int cl = wn * 64 + j * 16 + lrow;
                const int rl = wm * 64 + i * 16 + lk * 4;
                ushort4 pk;
                pk.x = f2bf(acc[i][j][0]); pk.y = f2bf(acc[i][j][1]);
                pk.z = f2bf(acc[i][j][2]); pk.w = f2bf(acc[i][j][3]);
                *(ushort4*)&smem[cl * 132 + rl] = pk;
            }
        __syncthreads();
        const int c = t >> 1, h2 = t & 1;
        unsigned short* vtp = Vt + (long)(n0l + c) * M_SZ + m0 + h2 * 64;
#pragma unroll
        for (int j = 0; j < 8; ++j) {
            union { struct { ushort4 a, b; } s; ix4 v; } u;
            u.s.a = *(const ushort4*)&smem[c * 132 + h2 * 64 + j * 8];
            u.s.b = *(const ushort4*)&smem[c * 132 + h2 * 64 + j * 8 + 4];
            *(ix4*)(vtp + j * 8) = u.v;
        }
    }
}

// ---------------- GEMM: C[M][N] = A[M][K] * Bw[N][K]^T (R6-verified 128x128) ----------------
template<int OUT_BF16>
__global__ __launch_bounds__(256) void gemm_bt(const unsigned short* __restrict__ A,
                                               const unsigned short* __restrict__ Bw,
                                               void* __restrict__ Cout,
                                               int M, int N, int K, float scale) {
    __shared__ __align__(16) unsigned short As[2][128 * 32];
    __shared__ __align__(16) unsigned short Bs[2][128 * 32];

    const int t = threadIdx.x;
    const int lane = t & 63;
    const int w = t >> 6;
    const int wm = w >> 1, wn = w & 1;
    const int lrow = lane & 15, lk = lane >> 4;
    const int m0 = blockIdx.y * 128, n0 = blockIdx.x * 128;

    fx4 acc[4][4] = {};

    const int arow = t >> 2;
    const int acol = (t & 3) * 8;
    const unsigned short* Ag = A + (long)(m0 + arow) * K + acol;
    const unsigned short* Bg = Bw + (long)(n0 + arow) * K + acol;
    const int lds0 = t * 8;
    const int nk = K / 32;

    async16(Ag, &As[0][lds0]);
    async16(Ag + 64 * K, &As[0][lds0 + 64 * 32]);
    async16(Bg, &Bs[0][lds0]);
    async16(Bg + 64 * K, &Bs[0][lds0 + 64 * 32]);

    for (int kt = 0; kt < nk; ++kt) {
        const int cur = kt & 1;
        if (kt + 1 < nk) {
            const int ko = (kt + 1) * 32;
            async16(Ag + ko, &As[cur ^ 1][lds0]);
            async16(Ag + 64 * K + ko, &As[cur ^ 1][lds0 + 64 * 32]);
            async16(Bg + ko, &Bs[cur ^ 1][lds0]);
            async16(Bg + 64 * K + ko, &Bs[cur ^ 1][lds0 + 64 * 32]);
            asm volatile("s_waitcnt vmcnt(4)" ::: "memory");
        } else {
            asm volatile("s_waitcnt vmcnt(0)" ::: "memory");
        }
        __syncthreads();

        s16x8 af[4], bf[4];
#pragma unroll
        for (int i = 0; i < 4; ++i)
            af[i] = *(const s16x8*)&As[cur][(wm * 64 + i * 16 + lrow) * 32 + lk * 8];
#pragma unroll
        for (int i = 0; i < 4; ++i)
            bf[i] = *(const s16x8*)&Bs[cur][(wn * 64 + i * 16 + lrow) * 32 + lk * 8];
#pragma unroll
        for (int i = 0; i < 4; ++i)
#pragma unroll
            for (int j = 0; j < 4; ++j)
                acc[i][j] = __builtin_amdgcn_mfma_f32_16x16x32_bf16(af[i], bf[j], acc[i][j], 0, 0, 0);
        __syncthreads();
    }

#pragma unroll
    for (int i = 0; i < 4; ++i)
#pragma unroll
        for (int j = 0; j < 4; ++j)
#pragma unroll
            for (int r = 0; r < 4; ++r) {
                int row = m0 + wm * 64 + i * 16 + lk * 4 + r;
                int col = n0 + wn * 64 + j * 16 + lrow;
                float v = acc[i][j][r] * scale;
                if (OUT_BF16)
                    ((unsigned short*)Cout)[(long)row * N + col] = f2bf(v);
                else
                    ((float*)Cout)[(long)row * N + col] = v;
            }
}

// ---------------- Flash attention: swapped-S^T, 4 waves x 32 q-rows, Vt async16 staging ----------------
// (unchanged from R7 — verified at 99us)
__global__ __launch_bounds__(256, 4) void attn_kernel(const unsigned short* __restrict__ Q,
                                                      const unsigned short* __restrict__ Kb,
                                                      const unsigned short* __restrict__ Vt,
                                                      unsigned short* __restrict__ O) {
    __shared__ __align__(16) unsigned short Ks[2][64 * 64];   // [kv][d-chunk swz]
    __shared__ __align__(16) unsigned short Vs[2][64 * 64];   // [d][kv-chunk swz]
    __shared__ __align__(16) unsigned short Pl[4][16 * 72];   // per-wave P

    const int t = threadIdx.x;
    const int lane = t & 63, w = t >> 6;
    const int lrow = lane & 15, lk = lane >> 4;
    const int hb = blockIdx.x;
    const int h = hb & 15, b = hb >> 4;
    const int qb = 15 - blockIdx.y;                // heavy blocks dispatch first
    const int row0 = b * T_SZ;
    const int q0w = qb * 128 + w * 32;

    s16x8 qf[2][2];
#pragma unroll
    for (int hh = 0; hh < 2; ++hh) {
        const unsigned short* qp = Q + (long)(row0 + q0w + hh * 16 + lrow) * DM + h * DK + lk * 8;
        qf[hh][0] = *(const s16x8*)qp;
        qf[hh][1] = *(const s16x8*)(qp + 32);
    }

    fx4 acc[2][4] = {};
    float mrun[2] = {NINF, NINF}, lsum[2] = {0.f, 0.f};

    const int srow = t >> 3;                               // 0..31
    const int chk = (t & 7) ^ (srow & 7);                  // source pre-swizzle
    const unsigned short* Kg = Kb + (long)(row0 + srow) * DM + h * DK + chk * 8;
    const unsigned short* Vg = Vt + (long)(h * DK + srow) * M_SZ + row0 + chk * 8;
    unsigned short* Kl = &Ks[0][t * 8];
    unsigned short* Vl = &Vs[0][t * 8];

    const int nt = 2 * qb + 2;

    async16(Kg, Kl);
    async16(Kg + 32 * DM, Kl + 2048);
    async16(Vg, Vl);
    async16(Vg + 32 * (long)M_SZ, Vl + 2048);
    asm volatile("s_waitcnt vmcnt(0)" ::: "memory");
    __syncthreads();

    for (int kt = 0; kt < nt; ++kt) {
        const int cur = kt & 1;
        const bool pre = (kt + 1 < nt);
        if (pre) {
            const long koff = (long)(kt + 1) * 64 * DM;
            const int voff = (kt + 1) * 64;
            async16(Kg + koff, Kl + (cur ^ 1) * 4096);
            async16(Kg + koff + 32 * DM, Kl + (cur ^ 1) * 4096 + 2048);
            async16(Vg + voff, Vl + (cur ^ 1) * 4096);
            async16(Vg + voff + 32 * (long)M_SZ, Vl + (cur ^ 1) * 4096 + 2048);
        }
        const int kv0 = kt * 64;
        if (kv0 <= q0w + 31) {
            const char* ksb = (const char*)&Ks[cur][0];
            float p[2][4][4];
            float pm0 = NINF, pm1 = NINF;
#pragma unroll
            for (int sub = 0; sub < 4; ++sub) {
                const int kv0s = kv0 + sub * 16;
                if (kv0s <= q0w + 31) {          // half 1 active
                    const int rb = (sub * 16 + lrow) << 7;
                    const int sw = (lrow & 7) << 4;
                    const s16x8 kf0 = *(const s16x8*)(ksb + (rb + ((lk * 16) ^ sw)));
                    const s16x8 kf1 = *(const s16x8*)(ksb + (rb + ((64 + lk * 16) ^ sw)));
                    fx4 s1 = {};
                    s1 = __builtin_amdgcn_mfma_f32_16x16x32_bf16(kf0, qf[1][0], s1, 0, 0, 0);
                    s1 = __builtin_amdgcn_mfma_f32_16x16x32_bf16(kf1, qf[1][1], s1, 0, 0, 0);
                    if (kv0s + 15 > q0w + 16) {
#pragma unroll
                        for (int r = 0; r < 4; ++r)
                            if (kv0s + lk * 4 + r > q0w + 16 + lrow) s1[r] = NINF;
                    }
#pragma unroll
                    for (int r = 0; r < 4; ++r) { p[1][sub][r] = s1[r]; pm1 = fmaxf(pm1, s1[r]); }
                    if (kv0s <= q0w + 15) {      // half 0 active
                        fx4 s0 = {};
                        s0 = __builtin_amdgcn_mfma_f32_16x16x32_bf16(kf0, qf[0][0], s0, 0, 0, 0);
                        s0 = __builtin_amdgcn_mfma_f32_16x16x32_bf16(kf1, qf[0][1], s0, 0, 0, 0);
                        if (kv0s + 15 > q0w) {
#pragma unroll
                            for (int r = 0; r < 4; ++r)
                                if (kv0s + lk * 4 + r > q0w + lrow) s0[r] = NINF;
                        }
#pragma unroll
                        for (int r = 0; r < 4; ++r) { p[0][sub][r] = s0[r]; pm0 = fmaxf(pm0, s0[r]); }
                    } else {
#pragma unroll
                        for (int r = 0; r < 4; ++r) p[0][sub][r] = NINF;
                    }
                } else {
#pragma unroll
                    for (int r = 0; r < 4; ++r) { p[0][sub][r] = NINF; p[1][sub][r] = NINF; }
                }
            }
            float pmv[2] = {pm0, pm1};
#pragma unroll
            for (int hh = 0; hh < 2; ++hh) {
                float pm = pmv[hh];
                pm = fmaxf(pm, __shfl_xor(pm, 16));
                pm = fmaxf(pm, __shfl_xor(pm, 32));
                if (__any(pm > mrun[hh] + 8.f)) {
                    const float mnew = fmaxf(mrun[hh], pm);
                    const float sc = exp2f(mrun[hh] - mnew);
                    mrun[hh] = mnew;
                    lsum[hh] *= sc;
#pragma unroll
                    for (int r = 0; r < 4; ++r) {
                        const float scr = __shfl(sc, lk * 4 + r);
                        acc[hh][0][r] *= scr; acc[hh][1][r] *= scr;
                        acc[hh][2][r] *= scr; acc[hh][3][r] *= scr;
                    }
                }
                float ps = 0.f;
#pragma unroll
                for (int sub = 0; sub < 4; ++sub)
#pragma unroll
                    for (int r = 0; r < 4; ++r) {
                        const float pv = exp2f(p[hh][sub][r] - mrun[hh]);
                        p[hh][sub][r] = pv;
                        ps += pv;
                    }
                ps += __shfl_xor(ps, 16);
                ps += __shfl_xor(ps, 32);
                lsum[hh] += ps;
            }
            s16x8 pf[2][2];
#pragma unroll
            for (int hh = 0; hh < 2; ++hh) {
#pragma unroll
                for (int sub = 0; sub < 4; ++sub) {
                    uint2 pw;
                    pw.x = cvtpk(p[hh][sub][0], p[hh][sub][1]);
                    pw.y = cvtpk(p[hh][sub][2], p[hh][sub][3]);
                    *(uint2*)&Pl[w][lrow * 72 + sub * 16 + lk * 4] = pw;
                }
                pf[hh][0] = *(const s16x8*)&Pl[w][lrow * 72 + lk * 8];
                pf[hh][1] = *(const s16x8*)&Pl[w][lrow * 72 + 32 + lk * 8];
            }
#pragma unroll
            for (int s = 0; s < 2; ++s) {
                if (kv0 + s * 32 <= q0w + 31) {
                    const bool h0a = (kv0 + s * 32 <= q0w + 15);
#pragma unroll
                    for (int nf = 0; nf < 4; ++nf) {
                        const int d = nf * 16 + lrow;
                        const s16x8 vf = *(const s16x8*)&Vs[cur][d * 64 + (((s * 4 + lk) ^ (lrow & 7)) << 3)];
                        if (h0a)
                            acc[0][nf] = __builtin_amdgcn_mfma_f32_16x16x32_bf16(pf[0][s], vf, acc[0][nf], 0, 0, 0);
                        acc[1][nf] = __builtin_amdgcn_mfma_f32_16x16x32_bf16(pf[1][s], vf, acc[1][nf], 0, 0, 0);
                    }
                }
            }
        }
        asm volatile("s_waitcnt vmcnt(0)" ::: "memory");
        __syncthreads();
    }

#pragma unroll
    for (int hh = 0; hh < 2; ++hh) {
        float linv[4];
#pragma unroll
        for (int r = 0; r < 4; ++r) linv[r] = 1.f / __shfl(lsum[hh], lk * 4 + r);
        unsigned short* op = O + (long)(row0 + q0w + hh * 16) * DM + h * DK;
#pragma unroll
        for (int nf = 0; nf < 4; ++nf)
#pragma unroll
            for (int r = 0; r < 4; ++r)
                op[(long)(lk * 4 + r) * DM + nf * 16 + lrow] = f2bf(acc[hh][nf][r] * linv[r]);
    }
}

extern "C" void kernel_launch(void* const* d_in, const int* in_sizes, int n_in,
                              void* d_out, int out_size, void* d_ws, size_t ws_size,
                              hipStream_t stream) {
    const float* x  = (const float*)d_in[0];
    const float* Wq = (const float*)d_in[1];
    const float* Wk = (const float*)d_in[2];
    const float* Wv = (const float*)d_in[3];
    const float* Wo = (const float*)d_in[4];
    float* out = (float*)d_out;

    unsigned short* wsu = (unsigned short*)d_ws;
    unsigned short* xb  = wsu;                  // 8,388,608 elems
    unsigned short* wqb = xb + 8388608;         // 4 x 1,048,576 (contiguous: Wq,Wk,Wv,Wo)
    unsigned short* wob = wqb + 3 * 1048576;
    unsigned short* Qs  = wob + 1048576;        // 8,388,608
    unsigned short* Ob  = Qs + 8388608;         // 8,388,608 (attn output O)

    unsigned short* Kb = (unsigned short*)d_out;        // 16MB in d_out
    unsigned short* Vt = Kb + 8388608;                  // 16MB in d_out (V transposed)

    cast_f32_bf16<<<2048, 256, 0, stream>>>(x, xb, M_SZ * DM);
    cast_w4<<<dim3(256, 4), 256, 0, stream>>>(Wq, Wk, Wv, Wo, wqb);

    // fused Q/K/V projection: grid.x = 3 outputs x 8 col-tiles
    gemm_qkv<<<dim3(24, M_SZ / 128), 256, 0, stream>>>(xb, wqb, Qs, Kb, Vt);

    dim3 agrid(64, 16);                // x = (b,h) -> fixed XCD; y -> qb (heavy first)
    attn_kernel<<<agrid, 256, 0, stream>>>(Qs, Kb, Vt, Ob);

    dim3 ggrid(DM / 128, M_SZ / 128);  // (8, 64)
    gemm_bt<0><<<ggrid, 256, 0, stream>>>(Ob, wob, out, M_SZ, DM, DM, 1.f);
}

// Round 9
// 198.927 us; speedup vs baseline: 1.2932x; 1.0476x over previous
//
#include <hip/hip_runtime.h>

typedef __attribute__((ext_vector_type(8))) short s16x8;
typedef __attribute__((ext_vector_type(4))) float fx4;
typedef __attribute__((ext_vector_type(4))) int ix4;

#define B_SZ 4
#define T_SZ 2048
#define DM 1024
#define NH 16
#define DK 64
#define M_SZ (B_SZ * T_SZ)   // 8192
#define NINF (-__builtin_inff())
#define QSCALE (0.125f * 1.44269504088896340736f)

__device__ __forceinline__ unsigned short f2bf(float f) {
    unsigned int u = __float_as_uint(f);
    unsigned int r = u + 0x7fffu + ((u >> 16) & 1u);
    return (unsigned short)(r >> 16);
}

__device__ __forceinline__ unsigned cvtpk(float lo, float hi) {
    unsigned r;
    asm("v_cvt_pk_bf16_f32 %0, %1, %2" : "=v"(r) : "v"(lo), "v"(hi));
    return r;
}

__device__ __forceinline__ void async16(const unsigned short* g, unsigned short* l) {
    __builtin_amdgcn_global_load_lds(
        (const __attribute__((address_space(1))) unsigned int*)g,
        (__attribute__((address_space(3))) unsigned int*)l, 16, 0, 0);
}

// ---------------- cast fp32 -> bf16 (vectorized) ----------------
__global__ void cast_f32_bf16(const float* __restrict__ src, unsigned short* __restrict__ dst, int n) {
    int i = (blockIdx.x * blockDim.x + threadIdx.x) * 4;
    int stride = gridDim.x * blockDim.x * 4;
    for (; i + 3 < n; i += stride) {
        float4 v = *(const float4*)(src + i);
        ushort4 o;
        o.x = f2bf(v.x); o.y = f2bf(v.y); o.z = f2bf(v.z); o.w = f2bf(v.w);
        *(ushort4*)(dst + i) = o;
    }
}

// fused cast of the 4 weight matrices (dsts contiguous at dst + y*1M)
__global__ void cast_w4(const float* __restrict__ s0, const float* __restrict__ s1,
                        const float* __restrict__ s2, const float* __restrict__ s3,
                        unsigned short* __restrict__ dst) {
    const float* s = (blockIdx.y == 0) ? s0 : (blockIdx.y == 1) ? s1 : (blockIdx.y == 2) ? s2 : s3;
    unsigned short* d = dst + (size_t)blockIdx.y * (DM * DM);
    int i = (blockIdx.x * blockDim.x + threadIdx.x) * 4;
    int stride = gridDim.x * blockDim.x * 4;
    for (; i + 3 < DM * DM; i += stride) {
        float4 v = *(const float4*)(s + i);
        ushort4 o;
        o.x = f2bf(v.x); o.y = f2bf(v.y); o.z = f2bf(v.z); o.w = f2bf(v.w);
        *(ushort4*)(d + i) = o;
    }
}

// ---------------- fused QKV GEMM: 128x256 tile, BK=64, swizzled LDS, 1 barrier/tile ----------------
// grid (12, 64): cols [bx*256,+256) of C[8192][3072] vs W[3072][1024]^T.
// which = bx>>2: 0=Q (scaled) -> Qs, 1=K -> Kb, 2=V -> Vt (transposed via LDS epilogue).
// 512 threads = 8 waves (2M x 4N), per-wave 64x64 output (acc[4][4], verified frag shape).
// Staging: global_load_lds with chunk-XOR pre-swizzled source (rule 21, R3-verified scheme);
// reads use the same XOR -> 2-way bank conflicts (free). vmcnt(0)+barrier once per K-tile,
// drain covered by ~32 MFMA + 16 ds_read of compute issued since the stages.
__global__ __launch_bounds__(512, 2) void gemm_qkv256(const unsigned short* __restrict__ A,
                                                      const unsigned short* __restrict__ W,
                                                      unsigned short* __restrict__ Qs,
                                                      unsigned short* __restrict__ Kb,
                                                      unsigned short* __restrict__ Vt) {
    // S layout (elems): A buf0 [0,8192) buf1 [8192,16384); B buf0 [16384,32768) buf1 [32768,49152)
    // epilogue reuse: tl[256][132] = 33792 elems
    __shared__ __align__(16) unsigned short S[49152];   // 96 KB

    const int t = threadIdx.x;
    const int lane = t & 63, w = t >> 6;
    const int wm = w >> 2, wn = w & 3;          // 2 x 4 wave grid
    const int lrow = lane & 15, lk = lane >> 4;
    const int bx = blockIdx.x;                  // 0..11
    const int m0 = blockIdx.y * 128;
    const int K = DM;
    const int NKT = K / 64;                     // 16

    fx4 acc[4][4] = {};

    const int srow = t >> 3;                    // 0..63
    const int cs = (t & 7) ^ (srow & 7);        // swizzled source chunk
    const unsigned short* Ag = A + (long)(m0 + srow) * K + cs * 8;
    const unsigned short* Bg = W + (long)(bx * 256 + srow) * K + cs * 8;

    // prologue: tile 0 -> buf 0
    async16(Ag,           &S[t * 8]);
    async16(Ag + 64 * K,  &S[4096 + t * 8]);
    async16(Bg,           &S[16384 + t * 8]);
    async16(Bg + 64 * K,  &S[16384 + 4096 + t * 8]);
    async16(Bg + 128 * K, &S[16384 + 8192 + t * 8]);
    async16(Bg + 192 * K, &S[16384 + 12288 + t * 8]);
    asm volatile("s_waitcnt vmcnt(0)" ::: "memory");
    __syncthreads();

    for (int kt = 0; kt < NKT; ++kt) {
        const int cur = kt & 1;
        if (kt + 1 < NKT) {
            const int ko = (kt + 1) * 64;
            const int nbA = (cur ^ 1) * 8192;
            const int nbB = 16384 + (cur ^ 1) * 16384;
            async16(Ag + ko,           &S[nbA + t * 8]);
            async16(Ag + 64 * K + ko,  &S[nbA + 4096 + t * 8]);
            async16(Bg + ko,           &S[nbB + t * 8]);
            async16(Bg + 64 * K + ko,  &S[nbB + 4096 + t * 8]);
            async16(Bg + 128 * K + ko, &S[nbB + 8192 + t * 8]);
            async16(Bg + 192 * K + ko, &S[nbB + 12288 + t * 8]);
        }
        const unsigned short* Ab = &S[cur * 8192];
        const unsigned short* Bb = &S[16384 + cur * 16384];
#pragma unroll
        for (int kk = 0; kk < 2; ++kk) {
            const int sw = ((kk * 4 + lk) ^ (lrow & 7)) * 8;   // swizzled 16B chunk
            s16x8 af[4], bf[4];
#pragma unroll
            for (int mf = 0; mf < 4; ++mf)
                af[mf] = *(const s16x8*)&Ab[(wm * 64 + mf * 16 + lrow) * 64 + sw];
#pragma unroll
            for (int nf = 0; nf < 4; ++nf)
                bf[nf] = *(const s16x8*)&Bb[(wn * 64 + nf * 16 + lrow) * 64 + sw];
            __builtin_amdgcn_s_setprio(1);
#pragma unroll
            for (int mf = 0; mf < 4; ++mf)
#pragma unroll
                for (int nf = 0; nf < 4; ++nf)
                    acc[mf][nf] = __builtin_amdgcn_mfma_f32_16x16x32_bf16(af[mf], bf[nf], acc[mf][nf], 0, 0, 0);
            __builtin_amdgcn_s_setprio(0);
        }
        asm volatile("s_waitcnt vmcnt(0)" ::: "memory");
        __syncthreads();
    }

    const int which = bx >> 2;
    const int n0l = (bx & 3) * 256;
    if (which < 2) {
        unsigned short* dst = which ? Kb : Qs;
        const float sc = which ? 1.f : QSCALE;
#pragma unroll
        for (int mf = 0; mf < 4; ++mf)
#pragma unroll
            for (int nf = 0; nf < 4; ++nf)
#pragma unroll
                for (int r = 0; r < 4; ++r) {
                    int row = m0 + wm * 64 + mf * 16 + lk * 4 + r;
                    int col = n0l + wn * 64 + nf * 16 + lrow;
                    dst[(long)row * DM + col] = f2bf(acc[mf][nf][r] * sc);
                }
    } else {
        // V: transpose the 128x256 tile through LDS, store coalesced to Vt[DM][M_SZ]
#pragma unroll
        for (int mf = 0; mf < 4; ++mf)
#pragma unroll
            for (int nf = 0; nf < 4; ++nf) {
                const int cl = wn * 64 + nf * 16 + lrow;          // 0..255 (V col)
                const int rl = wm * 64 + mf * 16 + lk * 4;        // 0..127 (token row)
                ushort4 pk;
                pk.x = f2bf(acc[mf][nf][0]); pk.y = f2bf(acc[mf][nf][1]);
                pk.z = f2bf(acc[mf][nf][2]); pk.w = f2bf(acc[mf][nf][3]);
                *(ushort4*)&S[cl * 132 + rl] = pk;
            }
        __syncthreads();
        const int c = t >> 1, h2 = t & 1;                         // c 0..255
        unsigned short* vtp = Vt + (long)(n0l + c) * M_SZ + m0 + h2 * 64;
#pragma unroll
        for (int j = 0; j < 8; ++j) {
            union { struct { ushort4 a, b; } s; ix4 v; } u;
            u.s.a = *(const ushort4*)&S[c * 132 + h2 * 64 + j * 8];
            u.s.b = *(const ushort4*)&S[c * 132 + h2 * 64 + j * 8 + 4];
            *(ix4*)(vtp + j * 8) = u.v;
        }
    }
}

// ---------------- GEMM: C[M][N] = A[M][K] * Bw[N][K]^T (R6-verified 128x128) ----------------
template<int OUT_BF16>
__global__ __launch_bounds__(256) void gemm_bt(const unsigned short* __restrict__ A,
                                               const unsigned short* __restrict__ Bw,
                                               void* __restrict__ Cout,
                                               int M, int N, int K, float scale) {
    __shared__ __align__(16) unsigned short As[2][128 * 32];
    __shared__ __align__(16) unsigned short Bs[2][128 * 32];

    const int t = threadIdx.x;
    const int lane = t & 63;
    const int w = t >> 6;
    const int wm = w >> 1, wn = w & 1;
    const int lrow = lane & 15, lk = lane >> 4;
    const int m0 = blockIdx.y * 128, n0 = blockIdx.x * 128;

    fx4 acc[4][4] = {};

    const int arow = t >> 2;
    const int acol = (t & 3) * 8;
    const unsigned short* Ag = A + (long)(m0 + arow) * K + acol;
    const unsigned short* Bg = Bw + (long)(n0 + arow) * K + acol;
    const int lds0 = t * 8;
    const int nk = K / 32;

    async16(Ag, &As[0][lds0]);
    async16(Ag + 64 * K, &As[0][lds0 + 64 * 32]);
    async16(Bg, &Bs[0][lds0]);
    async16(Bg + 64 * K, &Bs[0][lds0 + 64 * 32]);

    for (int kt = 0; kt < nk; ++kt) {
        const int cur = kt & 1;
        if (kt + 1 < nk) {
            const int ko = (kt + 1) * 32;
            async16(Ag + ko, &As[cur ^ 1][lds0]);
            async16(Ag + 64 * K + ko, &As[cur ^ 1][lds0 + 64 * 32]);
            async16(Bg + ko, &Bs[cur ^ 1][lds0]);
            async16(Bg + 64 * K + ko, &Bs[cur ^ 1][lds0 + 64 * 32]);
            asm volatile("s_waitcnt vmcnt(4)" ::: "memory");
        } else {
            asm volatile("s_waitcnt vmcnt(0)" ::: "memory");
        }
        __syncthreads();

        s16x8 af[4], bf[4];
#pragma unroll
        for (int i = 0; i < 4; ++i)
            af[i] = *(const s16x8*)&As[cur][(wm * 64 + i * 16 + lrow) * 32 + lk * 8];
#pragma unroll
        for (int i = 0; i < 4; ++i)
            bf[i] = *(const s16x8*)&Bs[cur][(wn * 64 + i * 16 + lrow) * 32 + lk * 8];
#pragma unroll
        for (int i = 0; i < 4; ++i)
#pragma unroll
            for (int j = 0; j < 4; ++j)
                acc[i][j] = __builtin_amdgcn_mfma_f32_16x16x32_bf16(af[i], bf[j], acc[i][j], 0, 0, 0);
        __syncthreads();
    }

#pragma unroll
    for (int i = 0; i < 4; ++i)
#pragma unroll
        for (int j = 0; j < 4; ++j)
#pragma unroll
            for (int r = 0; r < 4; ++r) {
                int row = m0 + wm * 64 + i * 16 + lk * 4 + r;
                int col = n0 + wn * 64 + j * 16 + lrow;
                float v = acc[i][j][r] * scale;
                if (OUT_BF16)
                    ((unsigned short*)Cout)[(long)row * N + col] = f2bf(v);
                else
                    ((float*)Cout)[(long)row * N + col] = v;
            }
}

// ---------------- Flash attention (unchanged — verified at 99us) ----------------
__global__ __launch_bounds__(256, 4) void attn_kernel(const unsigned short* __restrict__ Q,
                                                      const unsigned short* __restrict__ Kb,
                                                      const unsigned short* __restrict__ Vt,
                                                      unsigned short* __restrict__ O) {
    __shared__ __align__(16) unsigned short Ks[2][64 * 64];   // [kv][d-chunk swz]
    __shared__ __align__(16) unsigned short Vs[2][64 * 64];   // [d][kv-chunk swz]
    __shared__ __align__(16) unsigned short Pl[4][16 * 72];   // per-wave P

    const int t = threadIdx.x;
    const int lane = t & 63, w = t >> 6;
    const int lrow = lane & 15, lk = lane >> 4;
    const int hb = blockIdx.x;
    const int h = hb & 15, b = hb >> 4;
    const int qb = 15 - blockIdx.y;                // heavy blocks dispatch first
    const int row0 = b * T_SZ;
    const int q0w = qb * 128 + w * 32;

    s16x8 qf[2][2];
#pragma unroll
    for (int hh = 0; hh < 2; ++hh) {
        const unsigned short* qp = Q + (long)(row0 + q0w + hh * 16 + lrow) * DM + h * DK + lk * 8;
        qf[hh][0] = *(const s16x8*)qp;
        qf[hh][1] = *(const s16x8*)(qp + 32);
    }

    fx4 acc[2][4] = {};
    float mrun[2] = {NINF, NINF}, lsum[2] = {0.f, 0.f};

    const int srow = t >> 3;                               // 0..31
    const int chk = (t & 7) ^ (srow & 7);                  // source pre-swizzle
    const unsigned short* Kg = Kb + (long)(row0 + srow) * DM + h * DK + chk * 8;
    const unsigned short* Vg = Vt + (long)(h * DK + srow) * M_SZ + row0 + chk * 8;
    unsigned short* Kl = &Ks[0][t * 8];
    unsigned short* Vl = &Vs[0][t * 8];

    const int nt = 2 * qb + 2;

    async16(Kg, Kl);
    async16(Kg + 32 * DM, Kl + 2048);
    async16(Vg, Vl);
    async16(Vg + 32 * (long)M_SZ, Vl + 2048);
    asm volatile("s_waitcnt vmcnt(0)" ::: "memory");
    __syncthreads();

    for (int kt = 0; kt < nt; ++kt) {
        const int cur = kt & 1;
        const bool pre = (kt + 1 < nt);
        if (pre) {
            const long koff = (long)(kt + 1) * 64 * DM;
            const int voff = (kt + 1) * 64;
            async16(Kg + koff, Kl + (cur ^ 1) * 4096);
            async16(Kg + koff + 32 * DM, Kl + (cur ^ 1) * 4096 + 2048);
            async16(Vg + voff, Vl + (cur ^ 1) * 4096);
            async16(Vg + voff + 32 * (long)M_SZ, Vl + (cur ^ 1) * 4096 + 2048);
        }
        const int kv0 = kt * 64;
        if (kv0 <= q0w + 31) {
            const char* ksb = (const char*)&Ks[cur][0];
            float p[2][4][4];
            float pm0 = NINF, pm1 = NINF;
#pragma unroll
            for (int sub = 0; sub < 4; ++sub) {
                const int kv0s = kv0 + sub * 16;
                if (kv0s <= q0w + 31) {          // half 1 active
                    const int rb = (sub * 16 + lrow) << 7;
                    const int sw = (lrow & 7) << 4;
                    const s16x8 kf0 = *(const s16x8*)(ksb + (rb + ((lk * 16) ^ sw)));
                    const s16x8 kf1 = *(const s16x8*)(ksb + (rb + ((64 + lk * 16) ^ sw)));
                    fx4 s1 = {};
                    s1 = __builtin_amdgcn_mfma_f32_16x16x32_bf16(kf0, qf[1][0], s1, 0, 0, 0);
                    s1 = __builtin_amdgcn_mfma_f32_16x16x32_bf16(kf1, qf[1][1], s1, 0, 0, 0);
                    if (kv0s + 15 > q0w + 16) {
#pragma unroll
                        for (int r = 0; r < 4; ++r)
                            if (kv0s + lk * 4 + r > q0w + 16 + lrow) s1[r] = NINF;
                    }
#pragma unroll
                    for (int r = 0; r < 4; ++r) { p[1][sub][r] = s1[r]; pm1 = fmaxf(pm1, s1[r]); }
                    if (kv0s <= q0w + 15) {      // half 0 active
                        fx4 s0 = {};
                        s0 = __builtin_amdgcn_mfma_f32_16x16x32_bf16(kf0, qf[0][0], s0, 0, 0, 0);
                        s0 = __builtin_amdgcn_mfma_f32_16x16x32_bf16(kf1, qf[0][1], s0, 0, 0, 0);
                        if (kv0s + 15 > q0w) {
#pragma unroll
                            for (int r = 0; r < 4; ++r)
                                if (kv0s + lk * 4 + r > q0w + lrow) s0[r] = NINF;
                        }
#pragma unroll
                        for (int r = 0; r < 4; ++r) { p[0][sub][r] = s0[r]; pm0 = fmaxf(pm0, s0[r]); }
                    } else {
#pragma unroll
                        for (int r = 0; r < 4; ++r) p[0][sub][r] = NINF;
                    }
                } else {
#pragma unroll
                    for (int r = 0; r < 4; ++r) { p[0][sub][r] = NINF; p[1][sub][r] = NINF; }
                }
            }
            float pmv[2] = {pm0, pm1};
#pragma unroll
            for (int hh = 0; hh < 2; ++hh) {
                float pm = pmv[hh];
                pm = fmaxf(pm, __shfl_xor(pm, 16));
                pm = fmaxf(pm, __shfl_xor(pm, 32));
                if (__any(pm > mrun[hh] + 8.f)) {
                    const float mnew = fmaxf(mrun[hh], pm);
                    const float sc = exp2f(mrun[hh] - mnew);
                    mrun[hh] = mnew;
                    lsum[hh] *= sc;
#pragma unroll
                    for (int r = 0; r < 4; ++r) {
                        const float scr = __shfl(sc, lk * 4 + r);
                        acc[hh][0][r] *= scr; acc[hh][1][r] *= scr;
                        acc[hh][2][r] *= scr; acc[hh][3][r] *= scr;
                    }
                }
                float ps = 0.f;
#pragma unroll
                for (int sub = 0; sub < 4; ++sub)
#pragma unroll
                    for (int r = 0; r < 4; ++r) {
                        const float pv = exp2f(p[hh][sub][r] - mrun[hh]);
                        p[hh][sub][r] = pv;
                        ps += pv;
                    }
                ps += __shfl_xor(ps, 16);
                ps += __shfl_xor(ps, 32);
                lsum[hh] += ps;
            }
            s16x8 pf[2][2];
#pragma unroll
            for (int hh = 0; hh < 2; ++hh) {
#pragma unroll
                for (int sub = 0; sub < 4; ++sub) {
                    uint2 pw;
                    pw.x = cvtpk(p[hh][sub][0], p[hh][sub][1]);
                    pw.y = cvtpk(p[hh][sub][2], p[hh][sub][3]);
                    *(uint2*)&Pl[w][lrow * 72 + sub * 16 + lk * 4] = pw;
                }
                pf[hh][0] = *(const s16x8*)&Pl[w][lrow * 72 + lk * 8];
                pf[hh][1] = *(const s16x8*)&Pl[w][lrow * 72 + 32 + lk * 8];
            }
#pragma unroll
            for (int s = 0; s < 2; ++s) {
                if (kv0 + s * 32 <= q0w + 31) {
                    const bool h0a = (kv0 + s * 32 <= q0w + 15);
#pragma unroll
                    for (int nf = 0; nf < 4; ++nf) {
                        const int d = nf * 16 + lrow;
                        const s16x8 vf = *(const s16x8*)&Vs[cur][d * 64 + (((s * 4 + lk) ^ (lrow & 7)) << 3)];
                        if (h0a)
                            acc[0][nf] = __builtin_amdgcn_mfma_f32_16x16x32_bf16(pf[0][s], vf, acc[0][nf], 0, 0, 0);
                        acc[1][nf] = __builtin_amdgcn_mfma_f32_16x16x32_bf16(pf[1][s], vf, acc[1][nf], 0, 0, 0);
                    }
                }
            }
        }
        asm volatile("s_waitcnt vmcnt(0)" ::: "memory");
        __syncthreads();
    }

#pragma unroll
    for (int hh = 0; hh < 2; ++hh) {
        float linv[4];
#pragma unroll
        for (int r = 0; r < 4; ++r) linv[r] = 1.f / __shfl(lsum[hh], lk * 4 + r);
        unsigned short* op = O + (long)(row0 + q0w + hh * 16) * DM + h * DK;
#pragma unroll
        for (int nf = 0; nf < 4; ++nf)
#pragma unroll
            for (int r = 0; r < 4; ++r)
                op[(long)(lk * 4 + r) * DM + nf * 16 + lrow] = f2bf(acc[hh][nf][r] * linv[r]);
    }
}

extern "C" void kernel_launch(void* const* d_in, const int* in_sizes, int n_in,
                              void* d_out, int out_size, void* d_ws, size_t ws_size,
                              hipStream_t stream) {
    const float* x  = (const float*)d_in[0];
    const float* Wq = (const float*)d_in[1];
    const float* Wk = (const float*)d_in[2];
    const float* Wv = (const float*)d_in[3];
    const float* Wo = (const float*)d_in[4];
    float* out = (float*)d_out;

    unsigned short* wsu = (unsigned short*)d_ws;
    unsigned short* xb  = wsu;                  // 8,388,608 elems
    unsigned short* wqb = xb + 8388608;         // 4 x 1,048,576 (contiguous: Wq,Wk,Wv,Wo)
    unsigned short* wob = wqb + 3 * 1048576;
    unsigned short* Qs  = wob + 1048576;        // 8,388,608
    unsigned short* Ob  = Qs + 8388608;         // 8,388,608 (attn output O)

    unsigned short* Kb = (unsigned short*)d_out;        // 16MB in d_out
    unsigned short* Vt = Kb + 8388608;                  // 16MB in d_out (V transposed)

    cast_f32_bf16<<<2048, 256, 0, stream>>>(x, xb, M_SZ * DM);
    cast_w4<<<dim3(256, 4), 256, 0, stream>>>(Wq, Wk, Wv, Wo, wqb);

    // fused Q/K/V projection as one N=3072 GEMM: 12 col-tiles x 64 row-tiles = 768 blocks
    gemm_qkv256<<<dim3(12, M_SZ / 128), 512, 0, stream>>>(xb, wqb, Qs, Kb, Vt);

    dim3 agrid(64, 16);                // x = (b,h) -> fixed XCD; y -> qb (heavy first)
    attn_kernel<<<agrid, 256, 0, stream>>>(Qs, Kb, Vt, Ob);

    dim3 ggrid(DM / 128, M_SZ / 128);  // (8, 64)
    gemm_bt<0><<<ggrid, 256, 0, stream>>>(Ob, wob, out, M_SZ, DM, DM, 1.f);
}